// Round 1
// baseline (1205.173 us; speedup 1.0000x reference)
//
#include <hip/hip_runtime.h>

// ---------------------------------------------------------------------------
// Hetero 2-layer GraphSAGE (dev<->task bipartite, 4 relations).
//
// Strategy:
//   L1: pre-transform node features (64->16) per relation BEFORE edge
//       aggregation (linearity of mean+matmul) -> 4x less scatter traffic.
//       Root terms use summed weight matrices (one matmul per node type).
//   Scatter: edge-parallel atomicAdd of 16-float rows; counts fused (L1 only,
//       reused for L2 since edges are identical).
//   L2: aggregate raw 16-dim hidden, then per-node 16->32 matmuls with
//       weights staged in LDS, writing straight to d_out.
//
// Workspace layout (floats), ~196.8 MB total:
//   [0        ..   500000) cnt_wr      (task)
//   [500000   ..  1000000) cnt_rv      (task)
//   [1000000  ..  1100000) cnt_wb      (dev)
//   [1100000  ..  1200000) cnt_rb      (dev)
//   [1200000  ..  9200000) agg1_wr     (task x16)
//   [9200000  .. 17200000) agg1_rv     (task x16)
//   [17200000 .. 18800000) agg1_wb     (dev  x16)
//   [18800000 .. 20400000) agg1_rb     (dev  x16)   <- memset [0,20.4M) zero
//   [20400000 .. 28400000) t1          (task x16)
//   [28400000 .. 30000000) d1          (dev  x16)
//   [30000000 .. 49200000) H region: h_wr(1.6M) h_rv(1.6M) h_wb(8M) h_rb(8M)
//        (dead after L1 scatter; re-zeroed and aliased as agg2_{wr,rv,wb,rb})
// Roots live in d_out (fully overwritten by the final out2 kernels):
//   root_t = d_out[0 .. 8M), root_d = d_out[8M .. 9.6M)
// ---------------------------------------------------------------------------

#define N_DEV  100000
#define N_TASK 500000
#define NEDGE  1000000

// ---- pretransform: out{A,B} = x @ W{A,B} (64x16), outC = x @ (WC1+WC2) ----
__global__ __launch_bounds__(256) void pretransform64to16x3(
    const float* __restrict__ x,
    const float* __restrict__ WA, const float* __restrict__ WB,
    const float* __restrict__ WC1, const float* __restrict__ WC2,
    float* __restrict__ outA, float* __restrict__ outB, float* __restrict__ outC,
    int n)
{
    __shared__ float wA[64 * 16];
    __shared__ float wB[64 * 16];
    __shared__ float wC[64 * 16];
    __shared__ float xs[16][68];   // 16 nodes x 64 feats, pad to 68 (bank spread)

    const int tid = threadIdx.x;
    for (int i = tid; i < 64 * 16; i += 256) {
        wA[i] = WA[i];
        wB[i] = WB[i];
        wC[i] = WC1[i] + WC2[i];
    }

    const int node0 = blockIdx.x * 16;
    {   // stage 16 node rows, coalesced float4 (256 threads x 1 float4 = 1024 f)
        const int r  = tid >> 4;        // node row 0..15
        const int c4 = tid & 15;        // float4 column
        const int node = node0 + r;
        float4 v = make_float4(0.f, 0.f, 0.f, 0.f);
        if (node < n)
            v = *reinterpret_cast<const float4*>(&x[(size_t)node * 64 + c4 * 4]);
        xs[r][c4 * 4 + 0] = v.x;
        xs[r][c4 * 4 + 1] = v.y;
        xs[r][c4 * 4 + 2] = v.z;
        xs[r][c4 * 4 + 3] = v.w;
    }
    __syncthreads();

    const int nl  = tid >> 4;
    const int col = tid & 15;
    const int node = node0 + nl;
    if (node >= n) return;

    float a = 0.f, b = 0.f, c = 0.f;
#pragma unroll
    for (int k = 0; k < 64; ++k) {
        const float xv = xs[nl][k];
        a = fmaf(xv, wA[k * 16 + col], a);
        b = fmaf(xv, wB[k * 16 + col], b);
        c = fmaf(xv, wC[k * 16 + col], c);
    }
    const size_t o = (size_t)node * 16 + col;
    outA[o] = a;
    outB[o] = b;
    outC[o] = c;
}

// ---- edge scatter: agg[dst] += h[src] (16 floats); optional count ----
__global__ __launch_bounds__(256) void scatter16(
    const float* __restrict__ h,
    const int* __restrict__ src, const int* __restrict__ dst,
    float* __restrict__ agg, float* __restrict__ cnt, int nE)
{
    const int tid = blockIdx.x * 256 + threadIdx.x;
    const int e = tid >> 4;
    const int j = tid & 15;
    if (e >= nE) return;
    const int s = src[e];
    const int d = dst[e];
    const float v = h[(size_t)s * 16 + j];
    atomicAdd(&agg[(size_t)d * 16 + j], v);
    if (j == 0 && cnt != nullptr) atomicAdd(&cnt[d], 1.0f);
}

// ---- combine L1: out = relu(aggA/cA + aggB/cB + root + blA + blB) ----
__global__ __launch_bounds__(256) void combine_relu16(
    const float* __restrict__ aggA, const float* __restrict__ cntA,
    const float* __restrict__ aggB, const float* __restrict__ cntB,
    const float* __restrict__ root,
    const float* __restrict__ blA, const float* __restrict__ blB,
    float* __restrict__ out, int n)
{
    const int tid = blockIdx.x * 256 + threadIdx.x;
    const int i = tid >> 4;
    const int j = tid & 15;
    if (i >= n) return;
    const float invA = 1.0f / fmaxf(cntA[i], 1.0f);
    const float invB = 1.0f / fmaxf(cntB[i], 1.0f);
    const float v = aggA[tid] * invA + aggB[tid] * invB + root[tid] + blA[j] + blB[j];
    out[tid] = fmaxf(v, 0.0f);
}

// ---- L2 output: out = (aggA/cA)@WA + (aggB/cB)@WB + xr@(WR1+WR2) + bA + bB ----
__global__ __launch_bounds__(256) void out2_16to32(
    const float* __restrict__ aggA, const float* __restrict__ cntA,
    const float* __restrict__ aggB, const float* __restrict__ cntB,
    const float* __restrict__ xroot,
    const float* __restrict__ WA, const float* __restrict__ WB,
    const float* __restrict__ WR1, const float* __restrict__ WR2,
    const float* __restrict__ bA, const float* __restrict__ bB,
    float* __restrict__ out, int n)
{
    __shared__ float wA[16 * 32];
    __shared__ float wB[16 * 32];
    __shared__ float wR[16 * 32];
    __shared__ float bs[32];

    const int tid = threadIdx.x;
    for (int i = tid; i < 16 * 32; i += 256) {
        wA[i] = WA[i];
        wB[i] = WB[i];
        wR[i] = WR1[i] + WR2[i];
    }
    if (tid < 32) bs[tid] = bA[tid] + bB[tid];
    __syncthreads();

    const int col = tid & 31;
    const int nl  = tid >> 5;          // 8 nodes per block
    const int node = blockIdx.x * 8 + nl;
    if (node >= n) return;

    const float invA = 1.0f / fmaxf(cntA[node], 1.0f);
    const float invB = 1.0f / fmaxf(cntB[node], 1.0f);
    float acc = bs[col];
#pragma unroll
    for (int k = 0; k < 16; ++k) {
        const size_t o = (size_t)node * 16 + k;
        acc = fmaf(aggA[o] * invA, wA[k * 32 + col], acc);
        acc = fmaf(aggB[o] * invB, wB[k * 32 + col], acc);
        acc = fmaf(xroot[o],       wR[k * 32 + col], acc);
    }
    out[(size_t)node * 32 + col] = acc;
}

extern "C" void kernel_launch(void* const* d_in, const int* in_sizes, int n_in,
                              void* d_out, int out_size, void* d_ws, size_t ws_size,
                              hipStream_t stream)
{
    // ---- inputs (setup_inputs dict order) ----
    const float* x_dev  = (const float*)d_in[0];
    const float* x_task = (const float*)d_in[1];
    const int* wr_src = (const int*)d_in[2];
    const int* wr_dst = (const int*)d_in[3];
    const int* rv_src = (const int*)d_in[4];
    const int* rv_dst = (const int*)d_in[5];
    const int* wb_src = (const int*)d_in[6];
    const int* wb_dst = (const int*)d_in[7];
    const int* rb_src = (const int*)d_in[8];
    const int* rb_dst = (const int*)d_in[9];
    // layer 1: wr(10-12) rv(13-15) wb(16-18) rb(19-21); layer 2: 22-33
    const float* p1wr_wl = (const float*)d_in[10];
    const float* p1wr_bl = (const float*)d_in[11];
    const float* p1wr_wr = (const float*)d_in[12];
    const float* p1rv_wl = (const float*)d_in[13];
    const float* p1rv_bl = (const float*)d_in[14];
    const float* p1rv_wr = (const float*)d_in[15];
    const float* p1wb_wl = (const float*)d_in[16];
    const float* p1wb_bl = (const float*)d_in[17];
    const float* p1wb_wr = (const float*)d_in[18];
    const float* p1rb_wl = (const float*)d_in[19];
    const float* p1rb_bl = (const float*)d_in[20];
    const float* p1rb_wr = (const float*)d_in[21];
    const float* p2wr_wl = (const float*)d_in[22];
    const float* p2wr_bl = (const float*)d_in[23];
    const float* p2wr_wr = (const float*)d_in[24];
    const float* p2rv_wl = (const float*)d_in[25];
    const float* p2rv_bl = (const float*)d_in[26];
    const float* p2rv_wr = (const float*)d_in[27];
    const float* p2wb_wl = (const float*)d_in[28];
    const float* p2wb_bl = (const float*)d_in[29];
    const float* p2wb_wr = (const float*)d_in[30];
    const float* p2rb_wl = (const float*)d_in[31];
    const float* p2rb_bl = (const float*)d_in[32];
    const float* p2rb_wr = (const float*)d_in[33];

    float* ws  = (float*)d_ws;
    float* out = (float*)d_out;

    // ---- workspace offsets (floats) ----
    float* cnt_wr  = ws + 0;
    float* cnt_rv  = ws + 500000;
    float* cnt_wb  = ws + 1000000;
    float* cnt_rb  = ws + 1100000;
    float* agg1_wr = ws + 1200000;     // task x16
    float* agg1_rv = ws + 9200000;     // task x16
    float* agg1_wb = ws + 17200000;    // dev  x16
    float* agg1_rb = ws + 18800000;    // dev  x16
    const size_t ZERO1_FLOATS = 20400000;
    float* t1 = ws + 20400000;         // task x16
    float* d1 = ws + 28400000;         // dev  x16
    // H region [30M, 49.2M): L1 pre-transforms, later aliased as L2 agg
    float* h_wr = ws + 30000000;       // dev  x16
    float* h_rv = ws + 31600000;       // dev  x16
    float* h_wb = ws + 33200000;       // task x16
    float* h_rb = ws + 41200000;       // task x16
    float* agg2_wr = ws + 30000000;    // task x16 (alias)
    float* agg2_rv = ws + 38000000;    // task x16 (alias)
    float* agg2_wb = ws + 46000000;    // dev  x16 (alias)
    float* agg2_rb = ws + 47600000;    // dev  x16 (alias)
    // roots live in d_out (fully overwritten by out2 at the end)
    float* root_t = out + 0;           // task x16 (8M floats)
    float* root_d = out + 8000000;     // dev  x16 (1.6M floats)

    const int scatter_grid = (NEDGE * 16) / 256;            // 62500

    // zero counts + L1 agg
    hipMemsetAsync(ws, 0, ZERO1_FLOATS * sizeof(float), stream);

    // L1 pre-transforms (+ summed root matmuls)
    pretransform64to16x3<<<(N_DEV + 15) / 16, 256, 0, stream>>>(
        x_dev, p1wr_wl, p1rv_wl, p1wb_wr, p1rb_wr, h_wr, h_rv, root_d, N_DEV);
    pretransform64to16x3<<<(N_TASK + 15) / 16, 256, 0, stream>>>(
        x_task, p1wb_wl, p1rb_wl, p1wr_wr, p1rv_wr, h_wb, h_rb, root_t, N_TASK);

    // L1 edge scatters (counts fused)
    scatter16<<<scatter_grid, 256, 0, stream>>>(h_wr, wr_src, wr_dst, agg1_wr, cnt_wr, NEDGE);
    scatter16<<<scatter_grid, 256, 0, stream>>>(h_rv, rv_src, rv_dst, agg1_rv, cnt_rv, NEDGE);
    scatter16<<<scatter_grid, 256, 0, stream>>>(h_wb, wb_src, wb_dst, agg1_wb, cnt_wb, NEDGE);
    scatter16<<<scatter_grid, 256, 0, stream>>>(h_rb, rb_src, rb_dst, agg1_rb, cnt_rb, NEDGE);

    // L1 combine + relu
    combine_relu16<<<(N_TASK * 16) / 256, 256, 0, stream>>>(
        agg1_wr, cnt_wr, agg1_rv, cnt_rv, root_t, p1wr_bl, p1rv_bl, t1, N_TASK);
    combine_relu16<<<(N_DEV * 16) / 256, 256, 0, stream>>>(
        agg1_wb, cnt_wb, agg1_rb, cnt_rb, root_d, p1wb_bl, p1rb_bl, d1, N_DEV);

    // zero L2 agg (aliases H region)
    hipMemsetAsync(ws + 30000000, 0, (size_t)19200000 * sizeof(float), stream);

    // L2 edge scatters (reuse counts)
    scatter16<<<scatter_grid, 256, 0, stream>>>(d1, wr_src, wr_dst, agg2_wr, nullptr, NEDGE);
    scatter16<<<scatter_grid, 256, 0, stream>>>(d1, rv_src, rv_dst, agg2_rv, nullptr, NEDGE);
    scatter16<<<scatter_grid, 256, 0, stream>>>(t1, wb_src, wb_dst, agg2_wb, nullptr, NEDGE);
    scatter16<<<scatter_grid, 256, 0, stream>>>(t1, rb_src, rb_dst, agg2_rb, nullptr, NEDGE);

    // L2 combine + 16->32 output matmuls (write d_out: d2 first, then t2)
    out2_16to32<<<(N_TASK + 7) / 8, 256, 0, stream>>>(
        agg2_wr, cnt_wr, agg2_rv, cnt_rv, t1,
        p2wr_wl, p2rv_wl, p2wr_wr, p2rv_wr, p2wr_bl, p2rv_bl,
        out + (size_t)N_DEV * 32, N_TASK);
    out2_16to32<<<(N_DEV + 7) / 8, 256, 0, stream>>>(
        agg2_wb, cnt_wb, agg2_rb, cnt_rb, d1,
        p2wb_wl, p2rb_wl, p2wb_wr, p2rb_wr, p2wb_bl, p2rb_bl,
        out, N_DEV);
}